// Round 3
// baseline (292.941 us; speedup 1.0000x reference)
//
#include <hip/hip_runtime.h>
#include <hip/hip_bf16.h>

// GCN decoder, 4 dispatches:
//  1) prep_t0_k: blocks 0-255 compute msg0 = lat@W0+b0 (W0 transposed via LDS);
//                blocks 256+ transpose W1/W2/Wout to bf16 [fo][k].
//  2-4) agg_k<MODE,ADJW>: h = relu(adj@msg) + fused epilogue GEMM.
//       ADJW=0: read adj fp32, write back bf16 copy. ADJW=1: read bf16 adj.
//       MODE=0: epilogue = next transform (msg_out). MODE=1: output proj * mask.
// XCD swizzle: batch = blockIdx&7 -> each XCD keeps its batch's msg panel L2-hot.
//
// v4: DEPTH-4 register pipeline. v0/v3 had issue-to-consume distance of only
// ~0.75 iterations (set loaded at top of iter, consumed by storeTile at its
// end) -> every vmcnt wait paid nearly full load latency; T_iter ~ 1.7*L
// (10,700 cy/iter measured, all util counters <5%, grid-capped 2 blocks/CU so
// TLP can't hide it). Now 4 named register sets, loop unrolled x4 (all set/buf
// indices compile-time): load set[q%4]<-tile q+4; store set[(q+1)%4]->buf;
// mfma; lgkm-only barrier. Distance ~3.8 phases -> counted vmcnt waits see
// loads issued ~2 iterations earlier -> latency hidden, ~24 loads in flight.

typedef __bf16 bf16;
typedef __bf16 bf16x4 __attribute__((ext_vector_type(4)));
typedef __bf16 bf16x8 __attribute__((ext_vector_type(8)));
typedef float  f32x16 __attribute__((ext_vector_type(16)));
typedef float  f32x4  __attribute__((ext_vector_type(4)));

static __device__ inline f32x16 mfma32(bf16x8 a, bf16x8 b, f32x16 c) {
    return __builtin_amdgcn_mfma_f32_32x32x16_bf16(a, b, c, 0, 0, 0);
}

// Barrier that does NOT drain vmcnt: LDS stores must be complete (lgkmcnt 0),
// but global prefetch loads stay in flight. Memory clobbers pin LDS-op motion.
static __device__ inline void tile_barrier() {
    asm volatile("s_waitcnt lgkmcnt(0)" ::: "memory");
    __builtin_amdgcn_s_barrier();
    asm volatile("" ::: "memory");
}

#define NB   8
#define NN   2048
#define LAT  64
#define HID  128
#define ODIM 64
#define NT   32    // k-tiles per aggregation (2048 / 64)

// ---------------- dispatch 1: transform0 (blocks 0-255) + weight prep (blocks 256+) ----
__global__ __launch_bounds__(256) void prep_t0_k(
    const float* __restrict__ lat, const float* __restrict__ W0,
    const float* __restrict__ b0,
    const float* __restrict__ W1, const float* __restrict__ W2,
    const float* __restrict__ Wout,
    bf16* __restrict__ msgT, bf16* __restrict__ WT1,
    bf16* __restrict__ WT2, bf16* __restrict__ WoutT)
{
    __shared__ __align__(16) bf16 WTs[HID * 72];   // W0^T [fo][k], stride 72
    int tid = threadIdx.x;
    int blk = blockIdx.x;

    if (blk >= 256) {           // weight transposes (tiny)
        int i = (blk - 256) * 256 + tid;
        if (i < HID * HID) { int fo = i >> 7, k = i & 127; WT1[i] = (bf16)W1[k * HID + fo]; return; }
        i -= HID * HID;
        if (i < HID * HID) { int fo = i >> 7, k = i & 127; WT2[i] = (bf16)W2[k * HID + fo]; return; }
        i -= HID * HID;
        if (i < ODIM * HID) { int o = i >> 7, k = i & 127; WoutT[i] = (bf16)Wout[k * ODIM + o]; return; }
        return;
    }

    // stage W0^T into LDS (W0 is [64][128] row-major, coalesced fp32 reads)
    for (int i = tid; i < LAT * HID; i += 256) {
        int k = i >> 7, fo = i & 127;
        WTs[fo * 72 + k] = (bf16)W0[i];
    }
    __syncthreads();

    int l = tid & 63, w = tid >> 6;
    int lm = l & 31, lh = l >> 5;
    int g0 = blk * 64;
    int b  = g0 >> 11, nb = g0 & 2047;

    const bf16*  Wrow = &WTs[(w * 32 + lm) * 72 + lh * 8];
    const float* r0   = lat + (size_t)(g0 + lm) * LAT + lh * 8;
    const float* r1   = r0 + (size_t)32 * LAT;

    f32x16 acc0 = {}, acc1 = {};
#pragma unroll
    for (int k0 = 0; k0 < LAT; k0 += 16) {
        bf16x8 a = *(const bf16x8*)(Wrow + k0);
        f32x4 x0 = *(const f32x4*)(r0 + k0), x1 = *(const f32x4*)(r0 + k0 + 4);
        f32x4 y0 = *(const f32x4*)(r1 + k0), y1 = *(const f32x4*)(r1 + k0 + 4);
        bf16x8 v0, v1;
        v0[0]=(bf16)x0[0]; v0[1]=(bf16)x0[1]; v0[2]=(bf16)x0[2]; v0[3]=(bf16)x0[3];
        v0[4]=(bf16)x1[0]; v0[5]=(bf16)x1[1]; v0[6]=(bf16)x1[2]; v0[7]=(bf16)x1[3];
        v1[0]=(bf16)y0[0]; v1[1]=(bf16)y0[1]; v1[2]=(bf16)y0[2]; v1[3]=(bf16)y0[3];
        v1[4]=(bf16)y1[0]; v1[5]=(bf16)y1[1]; v1[6]=(bf16)y1[2]; v1[7]=(bf16)y1[3];
        acc0 = mfma32(a, v0, acc0);
        acc1 = mfma32(a, v1, acc1);
    }

    bf16* outb = msgT + (size_t)b * (HID * NN) + nb;
#pragma unroll
    for (int r = 0; r < 16; ++r) {
        int fo = w * 32 + (r & 3) + 8 * (r >> 2) + 4 * lh;
        float bv = b0[fo];
        outb[(size_t)fo * NN + lm]      = (bf16)(acc0[r] + bv);
        outb[(size_t)fo * NN + 32 + lm] = (bf16)(acc1[r] + bv);
    }
}

// ---------------- dispatches 2-4: fused aggregate ----------------
template<int MODE, int ADJW>
__global__ __launch_bounds__(256) void agg_k(
    const float* __restrict__ adjf, const bf16* __restrict__ adjbi,
    bf16* __restrict__ adjbo,
    const bf16* __restrict__ msgT, const bf16* __restrict__ WTn,
    const float* __restrict__ biasn, bf16* __restrict__ msg_out,
    const float* __restrict__ mask, float* __restrict__ out)
{
    __shared__ __align__(16) bf16 As[2][32 * 72];
    __shared__ __align__(16) bf16 Bs[2][128 * 72];
    __shared__ __align__(16) bf16 Hs[32 * 136];
    int tid = threadIdx.x;
    int l = tid & 63, w = tid >> 6;
    int lm = l & 31, lh = l >> 5;
    int b  = blockIdx.x & 7;            // XCD swizzle: batch b -> XCD b
    int m0 = (blockIdx.x >> 3) * 32;

    const bf16* msgb = msgT + (size_t)b * (HID * NN);
    int br = tid >> 3, bc = (tid & 7) * 8;
    const bf16* bsrc = msgb + (size_t)br * NN + bc;

    // A staging (fp32 variant): rows {ar, ar+16}, 16B chunks; 16 lanes = full 256B row chunk
    int ar = tid >> 4, ac = (tid & 15) * 4;
    const float* asrc = (ADJW == 0) ? adjf + (size_t)b * NN * NN + (size_t)(m0 + ar) * NN + ac : nullptr;
    bf16* adst = (ADJW == 0) ? adjbo + (size_t)b * NN * NN + (size_t)(m0 + ar) * NN + ac : nullptr;
    // A staging (bf16 variant): row ar8, 16B chunk; 8 lanes = full 128B row chunk
    int ar8 = tid >> 3, ac8 = (tid & 7) * 8;
    const bf16* asrcb = (ADJW == 1) ? adjbi + (size_t)b * NN * NN + (size_t)(m0 + ar8) * NN + ac8 : nullptr;

    // 4 named register sets (all indices compile-time after x4 unroll)
    f32x4  fa0[4], fa1[4];
    bf16x8 ba[4];
    bf16x8 pb[4][4];

    auto loadTile = [&](int set, int k) {
        if (ADJW == 0) {
            fa0[set] = *(const f32x4*)(asrc + k);
            fa1[set] = *(const f32x4*)(asrc + (size_t)16 * NN + k);
        } else {
            ba[set] = *(const bf16x8*)(asrcb + k);
        }
        pb[set][0] = *(const bf16x8*)(bsrc + k);
        pb[set][1] = *(const bf16x8*)(bsrc + (size_t)32 * NN + k);
        pb[set][2] = *(const bf16x8*)(bsrc + (size_t)64 * NN + k);
        pb[set][3] = *(const bf16x8*)(bsrc + (size_t)96 * NN + k);
    };
    auto storeTile = [&](int set, int buf, int k) {
        if (ADJW == 0) {
            bf16x4 v0, v1;
            v0[0]=(bf16)fa0[set][0]; v0[1]=(bf16)fa0[set][1]; v0[2]=(bf16)fa0[set][2]; v0[3]=(bf16)fa0[set][3];
            v1[0]=(bf16)fa1[set][0]; v1[1]=(bf16)fa1[set][1]; v1[2]=(bf16)fa1[set][2]; v1[3]=(bf16)fa1[set][3];
            *(bf16x4*)&As[buf][ar * 72 + ac]        = v0;
            *(bf16x4*)&As[buf][(ar + 16) * 72 + ac] = v1;
            *(bf16x4*)(adst + k)                    = v0;   // bf16 adj writeback
            *(bf16x4*)(adst + (size_t)16 * NN + k)  = v1;
        } else {
            *(bf16x8*)&As[buf][ar8 * 72 + ac8] = ba[set];
        }
        *(bf16x8*)&Bs[buf][br * 72 + bc]        = pb[set][0];
        *(bf16x8*)&Bs[buf][(br + 32) * 72 + bc] = pb[set][1];
        *(bf16x8*)&Bs[buf][(br + 64) * 72 + bc] = pb[set][2];
        *(bf16x8*)&Bs[buf][(br + 96) * 72 + bc] = pb[set][3];
    };

    f32x16 acc = {};
    auto mfmaTile = [&](int buf) {
        const bf16* Ac = &As[buf][lm * 72 + lh * 8];
        const bf16* Bc = &Bs[buf][(w * 32 + lm) * 72 + lh * 8];
#pragma unroll
        for (int s = 0; s < 4; ++s)
            acc = mfma32(*(const bf16x8*)(Ac + s * 16), *(const bf16x8*)(Bc + s * 16), acc);
    };

    // prologue: 4 tiles in flight; commit tile 0 to buf0
    loadTile(0, 0 * 64);
    loadTile(1, 1 * 64);
    loadTile(2, 2 * 64);
    loadTile(3, 3 * 64);
    storeTile(0, 0, 0 * 64);
    tile_barrier();

    // phase q: load set[q%4] <- tile q+4; store set[(q+1)%4] (tile q+1) -> buf[(q+1)&1];
    //          mfma buf[q&1] (tile q); barrier. Unrolled x4 so indices are static.
#define PHASE(U)                                                            \
    do {                                                                    \
        int q = qb + (U);                                                   \
        if (q + 4 < NT) loadTile((U), (q + 4) * 64);                        \
        if (q + 1 < NT) storeTile(((U) + 1) & 3, ((U) + 1) & 1, (q + 1) * 64); \
        mfmaTile((U) & 1);                                                  \
        tile_barrier();                                                     \
    } while (0)

#pragma unroll 1
    for (int qb = 0; qb < NT; qb += 4) {
        PHASE(0);
        PHASE(1);
        PHASE(2);
        PHASE(3);
    }
#undef PHASE

    // relu(h) -> LDS [node][feat]
#pragma unroll
    for (int r = 0; r < 16; ++r) {
        int row = (r & 3) + 8 * (r >> 2) + 4 * lh;
        float v = acc[r];
        Hs[row * 136 + w * 32 + lm] = (bf16)(v > 0.f ? v : 0.f);
    }
    __syncthreads();

    if (MODE == 0) {
        // msg_out[fo][m0+node] = WTn[fo][:] . h[node][:] + biasn[fo]
        const bf16* Arow = WTn + (size_t)(w * 32 + lm) * HID + lh * 8;
        const bf16* Brow = &Hs[lm * 136 + lh * 8];
        f32x16 acc2 = {};
#pragma unroll
        for (int s = 0; s < 8; ++s)
            acc2 = mfma32(*(const bf16x8*)(Arow + s * 16), *(const bf16x8*)(Brow + s * 16), acc2);
        bf16* outb = msg_out + (size_t)b * (HID * NN) + m0;
#pragma unroll
        for (int r = 0; r < 16; ++r) {
            int fo = w * 32 + (r & 3) + 8 * (r >> 2) + 4 * lh;
            outb[(size_t)fo * NN + lm] = (bf16)(acc2[r] + biasn[fo]);
        }
    } else {
        if (w < 2) {
            int ob = w * 32;
            const bf16* Arow = &Hs[lm * 136 + lh * 8];
            const bf16* Brow = WTn + (size_t)(ob + lm) * HID + lh * 8;
            f32x16 acc2 = {};
#pragma unroll
            for (int s = 0; s < 8; ++s)
                acc2 = mfma32(*(const bf16x8*)(Arow + s * 16), *(const bf16x8*)(Brow + s * 16), acc2);
            float bv = biasn[ob + lm];
#pragma unroll
            for (int r = 0; r < 16; ++r) {
                int node = (r & 3) + 8 * (r >> 2) + 4 * lh;
                int g = b * NN + m0 + node;
                out[(size_t)g * ODIM + ob + lm] = (acc2[r] + bv) * mask[g];
            }
        }
    }
}

extern "C" void kernel_launch(void* const* d_in, const int* in_sizes, int n_in,
                              void* d_out, int out_size, void* d_ws, size_t ws_size,
                              hipStream_t stream)
{
    const float* lat  = (const float*)d_in[0];
    const float* adj  = (const float*)d_in[1];
    const float* mask = (const float*)d_in[2];
    const float* W0   = (const float*)d_in[3];
    const float* b0   = (const float*)d_in[4];
    const float* W1   = (const float*)d_in[5];
    const float* b1   = (const float*)d_in[6];
    const float* W2   = (const float*)d_in[7];
    const float* b2   = (const float*)d_in[8];
    const float* Wout = (const float*)d_in[9];
    const float* bout = (const float*)d_in[10];
    float* out = (float*)d_out;

    char* ws = (char*)d_ws;
    bf16* msgA  = (bf16*)(ws + 0);            // 4 MiB
    bf16* msgB  = (bf16*)(ws + 4194304);      // 4 MiB
    bf16* adjbf = (bf16*)(ws + 8388608);      // 8*2048*2048*2 = 64 MiB
    bf16* WT1   = (bf16*)(ws + 75497472);     // 32 KiB
    bf16* WT2   = (bf16*)(ws + 75530240);     // 32 KiB
    bf16* WoutT = (bf16*)(ws + 75563008);     // 16 KiB

    // blocks 0-255: transform0; blocks 256-415: weight transposes (40960 elems)
    prep_t0_k<<<416, 256, 0, stream>>>(lat, W0, b0, W1, W2, Wout, msgA, WT1, WT2, WoutT);

    agg_k<0, 0><<<512, 256, 0, stream>>>(adj, nullptr, adjbf, msgA, WT1, b1, msgB, nullptr, nullptr);
    agg_k<0, 1><<<512, 256, 0, stream>>>(nullptr, adjbf, nullptr, msgB, WT2, b2, msgA, nullptr, nullptr);
    agg_k<1, 1><<<512, 256, 0, stream>>>(nullptr, adjbf, nullptr, msgA, WoutT, bout, nullptr, mask, out);
}

// Round 4
// 267.758 us; speedup vs baseline: 1.0941x; 1.0941x over previous
//
#include <hip/hip_runtime.h>
#include <hip/hip_bf16.h>

// GCN decoder, 4 dispatches:
//  1) prep_t0_k: blocks 0-255 compute msg0 = lat@W0+b0 (W0 transposed via LDS);
//                blocks 256+ transpose W1/W2/Wout to bf16 [fo][k].
//  2-4) agg_k<MODE,ADJW>: h = relu(adj@msg) + fused epilogue GEMM.
//       ADJW=0: read adj fp32, write back bf16 copy. ADJW=1: read bf16 adj.
//       MODE=0: epilogue = next transform (msg_out). MODE=1: output proj * mask.
// XCD swizzle: batch = blockIdx&7 -> each XCD keeps its batch's msg panel L2-hot.
//
// v5: M=64 / BK=128 consolidation. v0/v3/v4 (three different schedules) all
// pinned at ~9.3 B/cyc/CU delivered traffic -> the lever is per-CU byte
// volume, not the schedule. M=32 put 2 blocks/CU each re-reading the full
// B-panel: 1.8 MB/CU for agg00. Now one 512-thread block (8 waves, 2x4 wave
// grid) owns 64 rows x 128 feats with BK=128: 1.28 MB/CU (1.4x less), and
// 16 phases instead of 32 halves the per-phase latency/barrier overhead.
// LDS 122 KB static (As 34.8K + Bs 69.6K + Hs 17.4K), 1 block/CU, 8 waves/CU
// unchanged. Depth-2 named register sets + lgkm-only tile_barrier kept.

typedef __bf16 bf16;
typedef __bf16 bf16x4 __attribute__((ext_vector_type(4)));
typedef __bf16 bf16x8 __attribute__((ext_vector_type(8)));
typedef float  f32x16 __attribute__((ext_vector_type(16)));
typedef float  f32x4  __attribute__((ext_vector_type(4)));

static __device__ inline f32x16 mfma32(bf16x8 a, bf16x8 b, f32x16 c) {
    return __builtin_amdgcn_mfma_f32_32x32x16_bf16(a, b, c, 0, 0, 0);
}

// Barrier that does NOT drain vmcnt: LDS stores must be complete (lgkmcnt 0),
// but global prefetch loads stay in flight. Memory clobbers pin LDS-op motion.
static __device__ inline void tile_barrier() {
    asm volatile("s_waitcnt lgkmcnt(0)" ::: "memory");
    __builtin_amdgcn_s_barrier();
    asm volatile("" ::: "memory");
}

#define NB   8
#define NN   2048
#define LAT  64
#define HID  128
#define ODIM 64
#define BM   64    // rows per block
#define BK   128   // k per phase
#define NP   16    // phases (2048 / 128)
#define LDK  136   // LDS row stride (BK + 8)

// ---------------- dispatch 1: transform0 (blocks 0-255) + weight prep (blocks 256+) ----
__global__ __launch_bounds__(256) void prep_t0_k(
    const float* __restrict__ lat, const float* __restrict__ W0,
    const float* __restrict__ b0,
    const float* __restrict__ W1, const float* __restrict__ W2,
    const float* __restrict__ Wout,
    bf16* __restrict__ msgT, bf16* __restrict__ WT1,
    bf16* __restrict__ WT2, bf16* __restrict__ WoutT)
{
    __shared__ __align__(16) bf16 WTs[HID * 72];   // W0^T [fo][k], stride 72
    int tid = threadIdx.x;
    int blk = blockIdx.x;

    if (blk >= 256) {           // weight transposes (tiny)
        int i = (blk - 256) * 256 + tid;
        if (i < HID * HID) { int fo = i >> 7, k = i & 127; WT1[i] = (bf16)W1[k * HID + fo]; return; }
        i -= HID * HID;
        if (i < HID * HID) { int fo = i >> 7, k = i & 127; WT2[i] = (bf16)W2[k * HID + fo]; return; }
        i -= HID * HID;
        if (i < ODIM * HID) { int o = i >> 7, k = i & 127; WoutT[i] = (bf16)Wout[k * ODIM + o]; return; }
        return;
    }

    // stage W0^T into LDS (W0 is [64][128] row-major, coalesced fp32 reads)
    for (int i = tid; i < LAT * HID; i += 256) {
        int k = i >> 7, fo = i & 127;
        WTs[fo * 72 + k] = (bf16)W0[i];
    }
    __syncthreads();

    int l = tid & 63, w = tid >> 6;
    int lm = l & 31, lh = l >> 5;
    int g0 = blk * 64;
    int b  = g0 >> 11, nb = g0 & 2047;

    const bf16*  Wrow = &WTs[(w * 32 + lm) * 72 + lh * 8];
    const float* r0   = lat + (size_t)(g0 + lm) * LAT + lh * 8;
    const float* r1   = r0 + (size_t)32 * LAT;

    f32x16 acc0 = {}, acc1 = {};
#pragma unroll
    for (int k0 = 0; k0 < LAT; k0 += 16) {
        bf16x8 a = *(const bf16x8*)(Wrow + k0);
        f32x4 x0 = *(const f32x4*)(r0 + k0), x1 = *(const f32x4*)(r0 + k0 + 4);
        f32x4 y0 = *(const f32x4*)(r1 + k0), y1 = *(const f32x4*)(r1 + k0 + 4);
        bf16x8 v0, v1;
        v0[0]=(bf16)x0[0]; v0[1]=(bf16)x0[1]; v0[2]=(bf16)x0[2]; v0[3]=(bf16)x0[3];
        v0[4]=(bf16)x1[0]; v0[5]=(bf16)x1[1]; v0[6]=(bf16)x1[2]; v0[7]=(bf16)x1[3];
        v1[0]=(bf16)y0[0]; v1[1]=(bf16)y0[1]; v1[2]=(bf16)y0[2]; v1[3]=(bf16)y0[3];
        v1[4]=(bf16)y1[0]; v1[5]=(bf16)y1[1]; v1[6]=(bf16)y1[2]; v1[7]=(bf16)y1[3];
        acc0 = mfma32(a, v0, acc0);
        acc1 = mfma32(a, v1, acc1);
    }

    bf16* outb = msgT + (size_t)b * (HID * NN) + nb;
#pragma unroll
    for (int r = 0; r < 16; ++r) {
        int fo = w * 32 + (r & 3) + 8 * (r >> 2) + 4 * lh;
        float bv = b0[fo];
        outb[(size_t)fo * NN + lm]      = (bf16)(acc0[r] + bv);
        outb[(size_t)fo * NN + 32 + lm] = (bf16)(acc1[r] + bv);
    }
}

// ---------------- dispatches 2-4: fused aggregate ----------------
// Block: 512 threads = 8 waves (wave grid 2m x 4n), output 64 rows x 128 feats.
template<int MODE, int ADJW>
__global__ __launch_bounds__(512) void agg_k(
    const float* __restrict__ adjf, const bf16* __restrict__ adjbi,
    bf16* __restrict__ adjbo,
    const bf16* __restrict__ msgT, const bf16* __restrict__ WTn,
    const float* __restrict__ biasn, bf16* __restrict__ msg_out,
    const float* __restrict__ mask, float* __restrict__ out)
{
    __shared__ __align__(16) bf16 As[2][BM * LDK];    // 34.8 KB
    __shared__ __align__(16) bf16 Bs[2][HID * LDK];   // 69.6 KB
    __shared__ __align__(16) bf16 Hs[BM * LDK];       // 17.4 KB
    int tid = threadIdx.x;
    int l = tid & 63, w = tid >> 6;
    int lm = l & 31, lh = l >> 5;
    int wm = w >> 2, wn = w & 3;        // wave grid: 2 (m) x 4 (n)
    int b  = blockIdx.x & 7;            // XCD swizzle: batch b -> XCD b
    int m0 = (blockIdx.x >> 3) * BM;

    // B staging: msgT rows {br, br+64}, col chunks {bc8, bc8+64}: 4 x bf16x8 / thread
    const bf16* msgb = msgT + (size_t)b * (HID * NN);
    int br = tid >> 3, bc8 = (tid & 7) * 8;
    const bf16* bsrc = msgb + (size_t)br * NN + bc8;

    // A staging (fp32): row ar (64 rows), col chunks acf + g*32: 4 x f32x4 / thread
    int ar = tid >> 3, acf = (tid & 7) * 4;
    const float* asrc = (ADJW == 0) ? adjf + (size_t)b * NN * NN + (size_t)(m0 + ar) * NN + acf : nullptr;
    bf16* adst = (ADJW == 0) ? adjbo + (size_t)b * NN * NN + (size_t)(m0 + ar) * NN + acf : nullptr;
    // A staging (bf16): row ar, col chunks ac8 + g*64: 2 x bf16x8 / thread
    int ac8 = (tid & 7) * 8;
    const bf16* asrcb = (ADJW == 1) ? adjbi + (size_t)b * NN * NN + (size_t)(m0 + ar) * NN + ac8 : nullptr;

    // 2 named register sets (indices compile-time via x2 unroll)
    f32x4  fa[2][4];
    bf16x8 ba[2][2];
    bf16x8 pb[2][4];

    auto loadTile = [&](int set, int k) {
        if (ADJW == 0) {
#pragma unroll
            for (int g = 0; g < 4; ++g) fa[set][g] = *(const f32x4*)(asrc + k + g * 32);
        } else {
#pragma unroll
            for (int g = 0; g < 2; ++g) ba[set][g] = *(const bf16x8*)(asrcb + k + g * 64);
        }
#pragma unroll
        for (int h = 0; h < 2; ++h)
#pragma unroll
            for (int g = 0; g < 2; ++g)
                pb[set][h * 2 + g] = *(const bf16x8*)(bsrc + (size_t)(h * 64) * NN + k + g * 64);
    };
    auto storeTile = [&](int set, int buf, int k) {
        if (ADJW == 0) {
#pragma unroll
            for (int g = 0; g < 4; ++g) {
                bf16x4 v;
                v[0]=(bf16)fa[set][g][0]; v[1]=(bf16)fa[set][g][1];
                v[2]=(bf16)fa[set][g][2]; v[3]=(bf16)fa[set][g][3];
                *(bf16x4*)&As[buf][ar * LDK + acf + g * 32] = v;
                *(bf16x4*)(adst + k + g * 32)               = v;   // bf16 adj writeback
            }
        } else {
#pragma unroll
            for (int g = 0; g < 2; ++g)
                *(bf16x8*)&As[buf][ar * LDK + ac8 + g * 64] = ba[set][g];
        }
#pragma unroll
        for (int h = 0; h < 2; ++h)
#pragma unroll
            for (int g = 0; g < 2; ++g)
                *(bf16x8*)&Bs[buf][(br + h * 64) * LDK + bc8 + g * 64] = pb[set][h * 2 + g];
    };

    f32x16 acc = {};
    auto mfmaTile = [&](int buf) {
        const bf16* Ac = &As[buf][(wm * 32 + lm) * LDK + lh * 8];
        const bf16* Bc = &Bs[buf][(wn * 32 + lm) * LDK + lh * 8];
#pragma unroll
        for (int s = 0; s < 8; ++s)
            acc = mfma32(*(const bf16x8*)(Ac + s * 16), *(const bf16x8*)(Bc + s * 16), acc);
    };

    // prologue: tiles 0,1 in flight; commit tile 0
    loadTile(0, 0 * BK);
    loadTile(1, 1 * BK);
    storeTile(0, 0, 0 * BK);
    tile_barrier();

    // phase q: load set[q&1] <- tile q+2; store set[(q+1)&1] (tile q+1) -> buf[(q+1)&1];
    // mfma buf[q&1] (tile q); barrier.
#define PHASE(U)                                                               \
    do {                                                                       \
        int q = qb + (U);                                                      \
        if (q + 2 < NP) loadTile((U), (q + 2) * BK);                           \
        if (q + 1 < NP) storeTile(((U) + 1) & 1, ((U) + 1) & 1, (q + 1) * BK); \
        mfmaTile((U) & 1);                                                     \
        tile_barrier();                                                        \
    } while (0)

#pragma unroll 1
    for (int qb = 0; qb < NP; qb += 2) {
        PHASE(0);
        PHASE(1);
    }
#undef PHASE

    // relu(h) -> LDS [node][feat]; node = wm*32 + crow(r), feat = wn*32 + lm
#pragma unroll
    for (int r = 0; r < 16; ++r) {
        int row = wm * 32 + (r & 3) + 8 * (r >> 2) + 4 * lh;
        float v = acc[r];
        Hs[row * LDK + wn * 32 + lm] = (bf16)(v > 0.f ? v : 0.f);
    }
    __syncthreads();

    if (MODE == 0) {
        // msg_out[fo][m0+node] = WTn[fo][:] . h[node][:] + biasn[fo]
        // wave (wm,wn): fo block wn*32, node block wm*32
        const bf16* Arow = WTn + (size_t)(wn * 32 + lm) * HID + lh * 8;
        const bf16* Brow = &Hs[(wm * 32 + lm) * LDK + lh * 8];
        f32x16 acc2 = {};
#pragma unroll
        for (int s = 0; s < 8; ++s)
            acc2 = mfma32(*(const bf16x8*)(Arow + s * 16), *(const bf16x8*)(Brow + s * 16), acc2);
        bf16* outb = msg_out + (size_t)b * (HID * NN) + m0 + wm * 32;
#pragma unroll
        for (int r = 0; r < 16; ++r) {
            int fo = wn * 32 + (r & 3) + 8 * (r >> 2) + 4 * lh;
            outb[(size_t)fo * NN + lm] = (bf16)(acc2[r] + biasn[fo]);
        }
    } else {
        if (wn < 2) {
            int ob = wn * 32;
            const bf16* Arow = &Hs[(wm * 32 + lm) * LDK + lh * 8];
            const bf16* Brow = WTn + (size_t)(ob + lm) * HID + lh * 8;
            f32x16 acc2 = {};
#pragma unroll
            for (int s = 0; s < 8; ++s)
                acc2 = mfma32(*(const bf16x8*)(Arow + s * 16), *(const bf16x8*)(Brow + s * 16), acc2);
            float bv = biasn[ob + lm];
#pragma unroll
            for (int r = 0; r < 16; ++r) {
                int node = wm * 32 + (r & 3) + 8 * (r >> 2) + 4 * lh;
                int g = b * NN + m0 + node;
                out[(size_t)g * ODIM + ob + lm] = (acc2[r] + bv) * mask[g];
            }
        }
    }
}

extern "C" void kernel_launch(void* const* d_in, const int* in_sizes, int n_in,
                              void* d_out, int out_size, void* d_ws, size_t ws_size,
                              hipStream_t stream)
{
    const float* lat  = (const float*)d_in[0];
    const float* adj  = (const float*)d_in[1];
    const float* mask = (const float*)d_in[2];
    const float* W0   = (const float*)d_in[3];
    const float* b0   = (const float*)d_in[4];
    const float* W1   = (const float*)d_in[5];
    const float* b1   = (const float*)d_in[6];
    const float* W2   = (const float*)d_in[7];
    const float* b2   = (const float*)d_in[8];
    const float* Wout = (const float*)d_in[9];
    const float* bout = (const float*)d_in[10];
    float* out = (float*)d_out;

    char* ws = (char*)d_ws;
    bf16* msgA  = (bf16*)(ws + 0);            // 4 MiB
    bf16* msgB  = (bf16*)(ws + 4194304);      // 4 MiB
    bf16* adjbf = (bf16*)(ws + 8388608);      // 8*2048*2048*2 = 64 MiB
    bf16* WT1   = (bf16*)(ws + 75497472);     // 32 KiB
    bf16* WT2   = (bf16*)(ws + 75530240);     // 32 KiB
    bf16* WoutT = (bf16*)(ws + 75563008);     // 16 KiB

    // blocks 0-255: transform0; blocks 256-415: weight transposes (40960 elems)
    prep_t0_k<<<416, 256, 0, stream>>>(lat, W0, b0, W1, W2, Wout, msgA, WT1, WT2, WoutT);

    // 256 blocks = 32 m-tiles x 8 batches, 1 block/CU
    agg_k<0, 0><<<256, 512, 0, stream>>>(adj, nullptr, adjbf, msgA, WT1, b1, msgB, nullptr, nullptr);
    agg_k<0, 1><<<256, 512, 0, stream>>>(nullptr, adjbf, nullptr, msgB, WT2, b2, msgA, nullptr, nullptr);
    agg_k<1, 1><<<256, 512, 0, stream>>>(nullptr, adjbf, nullptr, msgA, WoutT, bout, nullptr, mask, out);
}